// Round 1
// 730.959 us; speedup vs baseline: 1.0523x; 1.0523x over previous
//
#include <hip/hip_runtime.h>
#include <hip/hip_bf16.h>

#define B_ 4
#define T_ 1024
#define DM 512
#define H_ 8
#define DK 64

typedef __attribute__((ext_vector_type(4))) float f32x4;
typedef __attribute__((ext_vector_type(8))) short bf16x8;

__device__ __forceinline__ unsigned short f2bf(float f) {
  __hip_bfloat16 h = __float2bfloat16(f);
  return *reinterpret_cast<unsigned short*>(&h);
}

// ---------------------------------------------------------------------------
// Generic f32 tiled GEMM: C[M,N] = X[M,K] @ op(W)
//  BLAY 0: W is [N,K] row-major (NT, x @ w.T) ; BLAY 1: W is [K,N] (NN, A @ V)
//  OMODE 0: row-major [M,N]
//  OMODE 1: qkv split: row r=(b,t), col c=(h,d) -> out[b,h,t,d]
//  OMODE 2: ctx: batch z=(b,h), row=t, col=d -> out[b,t,h*64+d]
//  OUTBF 1: output bf16 (only OMODE 1 uses it)
// ---------------------------------------------------------------------------
template<int BLAY, int OMODE, int OUTBF>
__global__ __launch_bounds__(256)
void gemm64(const float* __restrict__ X, const float* __restrict__ W,
            void* __restrict__ outv, int M, int N, int K,
            long xbatch, long wbatch) {
  float* out = (float*)outv;
  unsigned short* outb = (unsigned short*)outv;
  __shared__ float Xs[16][68];
  __shared__ float Ws[16][68];
  const int t = threadIdx.x;
  const long bz = blockIdx.z;
  X += bz * xbatch;
  W += bz * wbatch;
  const int n0 = blockIdx.x * 64, m0 = blockIdx.y * 64;
  const int tx = t & 15, ty = t >> 4;
  float acc[4][4] = {};
  for (int k0 = 0; k0 < K; k0 += 16) {
    {
      int m = t >> 2, ks = (t & 3) << 2;
      float4 v = *(const float4*)&X[(long)(m0 + m) * K + k0 + ks];
      Xs[ks + 0][m] = v.x; Xs[ks + 1][m] = v.y;
      Xs[ks + 2][m] = v.z; Xs[ks + 3][m] = v.w;
    }
    if (BLAY == 0) {
      int n = t >> 2, ks = (t & 3) << 2;
      float4 v = *(const float4*)&W[(long)(n0 + n) * K + k0 + ks];
      Ws[ks + 0][n] = v.x; Ws[ks + 1][n] = v.y;
      Ws[ks + 2][n] = v.z; Ws[ks + 3][n] = v.w;
    } else {
      int r = t >> 4, cs = (t & 15) << 2;
      *(float4*)&Ws[r][cs] = *(const float4*)&W[(long)(k0 + r) * N + n0 + cs];
    }
    __syncthreads();
#pragma unroll
    for (int kk = 0; kk < 16; ++kk) {
      float a[4], b[4];
      *(float4*)a = *(const float4*)&Xs[kk][ty << 2];
      *(float4*)b = *(const float4*)&Ws[kk][tx << 2];
#pragma unroll
      for (int i = 0; i < 4; ++i)
#pragma unroll
        for (int j = 0; j < 4; ++j)
          acc[i][j] += a[i] * b[j];
    }
    __syncthreads();
  }
#pragma unroll
  for (int i = 0; i < 4; ++i) {
    int r = m0 + (ty << 2) + i;
    int c0 = n0 + (tx << 2);
    float4 v = make_float4(acc[i][0], acc[i][1], acc[i][2], acc[i][3]);
    if (OMODE == 0) {
      *(float4*)&out[(long)r * N + c0] = v;
    } else if (OMODE == 1) {
      int b = r >> 10, tt = r & 1023, h = c0 >> 6, d = c0 & 63;
      long off = ((long)(b * H_ + h) * T_ + tt) * DK + d;
      if (OUTBF) {
        uint2 pk;
        pk.x = (unsigned)f2bf(v.x) | ((unsigned)f2bf(v.y) << 16);
        pk.y = (unsigned)f2bf(v.z) | ((unsigned)f2bf(v.w) << 16);
        *(uint2*)&outb[off] = pk;
      } else {
        *(float4*)&out[off] = v;
      }
    } else {
      int b = (int)bz >> 3, h = (int)bz & 7;
      *(float4*)&out[(long)(b * T_ + r) * DM + h * DK + c0] = v;
    }
  }
}

// ---------------------------------------------------------------------------
// Fused logits, MFMA everywhere. 512 threads / 8 waves per block.
//   Phase A : M = QK^T, processed as 4 HEAD PAIRS. Per pair: stage Q/K halos
//             for both heads (QK[2][2][48][72]), 9 MFMA jobs over 8 waves,
//             each job computes BOTH heads and writes C as packed u32
//             (2 bf16 channels per write -> half the LDS write instrs,
//             4-byte accesses instead of 2-byte).
//   Phase B0: stage prev halo channel-last -> P[36*36][8] bf16
//   Phase B1: Mt = conv3(prev)+tb as GEMM (K=8ch*9tap=72 pad 96) -> C[..][8+o]
//   Phase B2: Ma = conv3(cat(M,Mt))+ab as GEMM (K=144 pad 160),
//             logits = Ma/8 stored to the A region of d_out.
// Occupancy: LDS = 36992 (C) + 27648 (U) = 64640 B -> 2 blocks/CU at 8 waves
// = 16 waves/CU (~46%), vs 8 waves/CU (23%) for the 256-thread version.
// ---------------------------------------------------------------------------
__global__ __launch_bounds__(512)
void fused_logits(const unsigned short* __restrict__ Qp,
                  const unsigned short* __restrict__ Kp,
                  const float* __restrict__ prev,
                  const float* __restrict__ tw, const float* __restrict__ tb,
                  const float* __restrict__ aw, const float* __restrict__ ab,
                  float* __restrict__ logits) {
  __shared__ __align__(16) unsigned short C[34 * 34 * 16];  // 36992 B
  __shared__ __align__(16) unsigned char U[27648];  // QK[2][2][48][72] | P[1296][8]
  unsigned short (*QK)[2][48][72] = (unsigned short (*)[2][48][72])U;
  unsigned short* P = (unsigned short*)U;

  const int t = threadIdx.x;
  const int b = blockIdx.z, q0 = blockIdx.y * 32, k0 = blockIdx.x * 32;
  const int wave = t >> 6, lane = t & 63;
  const int lrow = lane & 15, quad = lane >> 4;
  const int o = lrow;              // out-channel for B fragments / D columns
  const int i0 = (quad & 1) * 8;   // conv2 channel-half per quad

  // ---- per-lane weight B-fragments (registers) ---------------------------
  bf16x8 W2f[5], W1f[3];
#pragma unroll
  for (int ks = 0; ks < 5; ++ks) {
    int kk0 = ks * 32 + quad * 8;           // tap = kk0>>4, i = (kk0&15)+j
    bf16x8 f = {0, 0, 0, 0, 0, 0, 0, 0};
    if (o < 8 && kk0 < 144) {
      int tap = kk0 >> 4, ib = kk0 & 15;
#pragma unroll
      for (int j = 0; j < 8; ++j)
        f[j] = (short)f2bf(aw[o * 144 + (ib + j) * 9 + tap]);
    }
    W2f[ks] = f;
  }
#pragma unroll
  for (int ks = 0; ks < 3; ++ks) {
    int kk0 = ks * 32 + quad * 8;           // tap = kk0>>3, i = j
    bf16x8 f = {0, 0, 0, 0, 0, 0, 0, 0};
    if (o < 8 && kk0 < 72) {
      int tap = kk0 >> 3;
#pragma unroll
      for (int j = 0; j < 8; ++j)
        f[j] = (short)f2bf(tw[o * 72 + j * 9 + tap]);
    }
    W1f[ks] = f;
  }
  const float tb_r = (o < 8) ? tb[o] : 0.f;
  const float ab_r = (o < 8) ? ab[o] : 0.f;

  // ---- Phase A: M halo, 4 head-pairs -------------------------------------
  for (int hp = 0; hp < 4; ++hp) {
    __syncthreads();                       // QK reuse across pairs
    // stage both heads: 2 heads * 2 arrays * 48 rows * 8 segs = 1536
    for (int c = t; c < 1536; c += 512) {
      int hh = (c >= 768) ? 1 : 0;
      int rem = c - hh * 768;
      int arr = (rem >= 384) ? 1 : 0;
      int rem2 = rem - arr * 384;
      int row = rem2 >> 3, seg = rem2 & 7;
      int srow = (arr ? k0 : q0) - 1 + row;
      bf16x8 v = {0, 0, 0, 0, 0, 0, 0, 0};
      if (srow >= 0 && srow < T_) {
        const unsigned short* src =
            (arr ? Kp : Qp) +
            ((long)((b * H_ + hp * 2 + hh) * T_ + srow)) * DK + seg * 8;
        v = *(const bf16x8*)src;
      }
      *(bf16x8*)&QK[hh][arr][row][seg * 8] = v;
    }
    __syncthreads();
    // 9 tile-jobs over 8 waves; each job does both heads of the pair
    for (int job = wave; job < 9; job += 8) {
      int ti = job / 3, tj = job - ti * 3;
      f32x4 acc0 = {0.f, 0.f, 0.f, 0.f};
      f32x4 acc1 = {0.f, 0.f, 0.f, 0.f};
#pragma unroll
      for (int c = 0; c < 2; ++c) {
        bf16x8 a0 = *(const bf16x8*)&QK[0][0][ti * 16 + lrow][c * 32 + quad * 8];
        bf16x8 b0 = *(const bf16x8*)&QK[0][1][tj * 16 + lrow][c * 32 + quad * 8];
        acc0 = __builtin_amdgcn_mfma_f32_16x16x32_bf16(a0, b0, acc0, 0, 0, 0);
        bf16x8 a1 = *(const bf16x8*)&QK[1][0][ti * 16 + lrow][c * 32 + quad * 8];
        bf16x8 b1 = *(const bf16x8*)&QK[1][1][tj * 16 + lrow][c * 32 + quad * 8];
        acc1 = __builtin_amdgcn_mfma_f32_16x16x32_bf16(a1, b1, acc1, 0, 0, 0);
      }
#pragma unroll
      for (int r = 0; r < 4; ++r) {
        int row = ti * 16 + quad * 4 + r, col = tj * 16 + lrow;
        if (row < 34 && col < 34) {
          unsigned pk =
              (unsigned)f2bf(acc0[r]) | ((unsigned)f2bf(acc1[r]) << 16);
          *(unsigned*)&C[(row * 34 + col) * 16 + hp * 2] = pk;
        }
      }
    }
  }
  __syncthreads();

  // ---- Phase B0: prev halo, channel-last ---------------------------------
  for (int p = t; p < 1296; p += 512) {    // 36*36 pixels
    int row = p / 36, col = p - row * 36;
    int gy = q0 - 2 + row, gx = k0 - 2 + col;
    bf16x8 v = {0, 0, 0, 0, 0, 0, 0, 0};
    if (gy >= 0 && gy < T_ && gx >= 0 && gx < T_) {
      const float* src = prev + ((long)(b * H_) * T_ + gy) * T_ + gx;
#pragma unroll
      for (int ch = 0; ch < 8; ++ch)
        v[ch] = (short)f2bf(src[(long)ch * T_ * T_]);
    }
    *(bf16x8*)&P[p * 8] = v;               // contiguous b128, conflict-free
  }
  __syncthreads();

  // ---- Phase B1: Mt = conv1(prev)+tb -> C channels 8..15 ------------------
  for (int mt = wave; mt < 73; mt += 8) {  // 1156 px in 73 m-tiles of 16
    int pin = mt * 16 + lrow;
    if (pin > 1155) pin = 1155;            // pad pixels: valid addr, discarded
    int yi = pin / 34, xi = pin - yi * 34;
    f32x4 acc = {0.f, 0.f, 0.f, 0.f};
#pragma unroll
    for (int ks = 0; ks < 3; ++ks) {
      int tap = ks * 4 + quad;             // kk0>>3
      if (tap > 8) tap = 8;                // pad k: B frag is 0
      int dy = tap / 3, dx = tap - dy * 3;
      bf16x8 av = *(const bf16x8*)&P[((yi + dy) * 36 + xi + dx) * 8];
      acc = __builtin_amdgcn_mfma_f32_16x16x32_bf16(av, W1f[ks], acc, 0, 0, 0);
    }
#pragma unroll
    for (int r = 0; r < 4; ++r) {
      int po = mt * 16 + quad * 4 + r;
      if (o < 8 && po < 1156) {
        int yo = po / 34, xo = po - yo * 34;
        int gy = q0 - 1 + yo, gx = k0 - 1 + xo;
        float val = (gy >= 0 && gy < T_ && gx >= 0 && gx < T_) ? acc[r] + tb_r
                                                               : 0.f;
        C[po * 16 + 8 + o] = f2bf(val);
      }
    }
  }
  __syncthreads();

  // ---- Phase B2: logits = (conv2(cat)+ab)/8 -> A region -------------------
  for (int mt = wave; mt < 64; mt += 8) {  // 1024 px in 64 m-tiles
    int pin = mt * 16 + lrow;
    int yi = pin >> 5, xi = pin & 31;
    f32x4 acc = {0.f, 0.f, 0.f, 0.f};
#pragma unroll
    for (int ks = 0; ks < 5; ++ks) {
      int tap = ks * 2 + (quad >> 1);      // kk0>>4
      if (tap > 8) tap = 8;                // pad k: B frag is 0
      int dy = tap / 3, dx = tap - dy * 3;
      bf16x8 av = *(const bf16x8*)&C[((yi + dy) * 34 + xi + dx) * 16 + i0];
      acc = __builtin_amdgcn_mfma_f32_16x16x32_bf16(av, W2f[ks], acc, 0, 0, 0);
    }
#pragma unroll
    for (int r = 0; r < 4; ++r) {
      int po = mt * 16 + quad * 4 + r;
      if (o < 8) {
        int yo = po >> 5, xo = po & 31;
        logits[((long)(b * H_ + o) * T_ + q0 + yo) * T_ + k0 + xo] =
            (acc[r] + ab_r) * 0.125f;
      }
    }
  }
}

// ---------------------------------------------------------------------------
// In-place masked softmax over the last dim (one row of 1024 per block).
// ---------------------------------------------------------------------------
__global__ __launch_bounds__(256)
void softmax_rows(float* __restrict__ A, const int* __restrict__ mask) {
  const int t = threadIdx.x;
  const int q = blockIdx.x, h = blockIdx.y, b = blockIdx.z;
  float* row = A + ((long)(b * H_ + h) * T_ + q) * T_;
  float4 v = *(float4*)&row[t * 4];
  int4 mv = *(const int4*)&mask[b * T_ + t * 4];
  v.x = (mv.x == 0) ? -1e9f : v.x;
  v.y = (mv.y == 0) ? -1e9f : v.y;
  v.z = (mv.z == 0) ? -1e9f : v.z;
  v.w = (mv.w == 0) ? -1e9f : v.w;

  __shared__ float r1[4], r2[4];
  const int wave = t >> 6, lane = t & 63;

  float mx4 = fmaxf(fmaxf(v.x, v.y), fmaxf(v.z, v.w));
  for (int of = 32; of > 0; of >>= 1) mx4 = fmaxf(mx4, __shfl_xor(mx4, of, 64));
  if (lane == 0) r1[wave] = mx4;
  __syncthreads();
  float mx = fmaxf(fmaxf(r1[0], r1[1]), fmaxf(r1[2], r1[3]));

  float e0 = __expf(v.x - mx), e1 = __expf(v.y - mx);
  float e2 = __expf(v.z - mx), e3 = __expf(v.w - mx);
  float s4 = (e0 + e1) + (e2 + e3);
  for (int of = 32; of > 0; of >>= 1) s4 += __shfl_xor(s4, of, 64);
  if (lane == 0) r2[wave] = s4;
  __syncthreads();
  float inv = 1.0f / (r2[0] + r2[1] + r2[2] + r2[3]);

  float4 ov;
  ov.x = e0 * inv; ov.y = e1 * inv; ov.z = e2 * inv; ov.w = e3 * inv;
  *(float4*)&row[t * 4] = ov;
}

// ---------------------------------------------------------------------------
extern "C" void kernel_launch(void* const* d_in, const int* in_sizes, int n_in,
                              void* d_out, int out_size, void* d_ws,
                              size_t ws_size, hipStream_t stream) {
  const float* q    = (const float*)d_in[0];
  const float* k    = (const float*)d_in[1];
  const float* v    = (const float*)d_in[2];
  const int*   mask = (const int*)  d_in[3];
  const float* prev = (const float*)d_in[4];
  const float* w_q  = (const float*)d_in[5];
  const float* w_k  = (const float*)d_in[6];
  const float* w_v  = (const float*)d_in[7];
  const float* w_o  = (const float*)d_in[8];
  const float* tw   = (const float*)d_in[9];
  const float* tb   = (const float*)d_in[10];
  const float* aw   = (const float*)d_in[11];
  const float* ab   = (const float*)d_in[12];

  float* out  = (float*)d_out;
  float* Aout = out + (long)B_ * T_ * DM;   // A region: (4,8,1024,1024) f32

  char* wsb = (char*)d_ws;                   // 24 MiB used
  unsigned short* Qp = (unsigned short*)wsb;                     // 4 MB bf16
  unsigned short* Kp = (unsigned short*)(wsb + (4L << 20));      // 4 MB bf16
  float* Vp  = (float*)(wsb + (8L << 20));                       // 8 MB f32
  float* ctx = (float*)(wsb + (16L << 20));                      // 8 MB f32

  dim3 blk(256);

  // Q/K projections -> bf16 head-split; V -> f32 head-split
  gemm64<0, 1, 1><<<dim3(8, 64, 1), blk, 0, stream>>>(q, w_q, Qp, 4096, 512, 512, 0, 0);
  gemm64<0, 1, 1><<<dim3(8, 64, 1), blk, 0, stream>>>(k, w_k, Kp, 4096, 512, 512, 0, 0);
  gemm64<0, 1, 0><<<dim3(8, 64, 1), blk, 0, stream>>>(v, w_v, Vp, 4096, 512, 512, 0, 0);

  // fused M + convs -> logits (into A region), all-MFMA, 512 threads
  fused_logits<<<dim3(32, 32, 4), dim3(512), 0, stream>>>(Qp, Kp, prev, tw, tb,
                                                          aw, ab, Aout);

  // softmax in place on A region
  softmax_rows<<<dim3(1024, 8, 4), blk, 0, stream>>>(Aout, mask);

  // ctx = A @ V (batched over (b,h)), output interleaved (b,t,h*64+d)
  gemm64<1, 2, 0><<<dim3(1, 16, 32), blk, 0, stream>>>(Aout, Vp, ctx, 1024, 64, 1024,
                                                       (long)T_ * T_, (long)T_ * DK);

  // final projection: ctx @ w_o^T -> out
  gemm64<0, 0, 0><<<dim3(8, 64, 1), blk, 0, stream>>>(ctx, w_o, out, 4096, 512, 512, 0, 0);
}

// Round 2
// 715.985 us; speedup vs baseline: 1.0743x; 1.0209x over previous
//
#include <hip/hip_runtime.h>
#include <hip/hip_bf16.h>

#define B_ 4
#define T_ 1024
#define DM 512
#define H_ 8
#define DK 64

typedef __attribute__((ext_vector_type(4))) float f32x4;
typedef __attribute__((ext_vector_type(8))) short bf16x8;

__device__ __forceinline__ unsigned short f2bf(float f) {
  __hip_bfloat16 h = __float2bfloat16(f);
  return *reinterpret_cast<unsigned short*>(&h);
}

// ---------------------------------------------------------------------------
// Generic f32 tiled GEMM: C[M,N] = X[M,K] @ op(W)
//  BLAY 0: W is [N,K] row-major (NT, x @ w.T) ; BLAY 1: W is [K,N] (NN, A @ V)
//  OMODE 0: row-major [M,N]
//  OMODE 1: qkv split: row r=(b,t), col c=(h,d) -> out[b,h,t,d]
//  OMODE 2: ctx: batch z=(b,h), row=t, col=d -> out[b,t,h*64+d]
//  OUTBF 1: output bf16 (only OMODE 1 uses it)
// ---------------------------------------------------------------------------
template<int BLAY, int OMODE, int OUTBF>
__global__ __launch_bounds__(256)
void gemm64(const float* __restrict__ X, const float* __restrict__ W,
            void* __restrict__ outv, int M, int N, int K,
            long xbatch, long wbatch) {
  float* out = (float*)outv;
  unsigned short* outb = (unsigned short*)outv;
  __shared__ float Xs[16][68];
  __shared__ float Ws[16][68];
  const int t = threadIdx.x;
  const long bz = blockIdx.z;
  X += bz * xbatch;
  W += bz * wbatch;
  const int n0 = blockIdx.x * 64, m0 = blockIdx.y * 64;
  const int tx = t & 15, ty = t >> 4;
  float acc[4][4] = {};
  for (int k0 = 0; k0 < K; k0 += 16) {
    {
      int m = t >> 2, ks = (t & 3) << 2;
      float4 v = *(const float4*)&X[(long)(m0 + m) * K + k0 + ks];
      Xs[ks + 0][m] = v.x; Xs[ks + 1][m] = v.y;
      Xs[ks + 2][m] = v.z; Xs[ks + 3][m] = v.w;
    }
    if (BLAY == 0) {
      int n = t >> 2, ks = (t & 3) << 2;
      float4 v = *(const float4*)&W[(long)(n0 + n) * K + k0 + ks];
      Ws[ks + 0][n] = v.x; Ws[ks + 1][n] = v.y;
      Ws[ks + 2][n] = v.z; Ws[ks + 3][n] = v.w;
    } else {
      int r = t >> 4, cs = (t & 15) << 2;
      *(float4*)&Ws[r][cs] = *(const float4*)&W[(long)(k0 + r) * N + n0 + cs];
    }
    __syncthreads();
#pragma unroll
    for (int kk = 0; kk < 16; ++kk) {
      float a[4], b[4];
      *(float4*)a = *(const float4*)&Xs[kk][ty << 2];
      *(float4*)b = *(const float4*)&Ws[kk][tx << 2];
#pragma unroll
      for (int i = 0; i < 4; ++i)
#pragma unroll
        for (int j = 0; j < 4; ++j)
          acc[i][j] += a[i] * b[j];
    }
    __syncthreads();
  }
#pragma unroll
  for (int i = 0; i < 4; ++i) {
    int r = m0 + (ty << 2) + i;
    int c0 = n0 + (tx << 2);
    float4 v = make_float4(acc[i][0], acc[i][1], acc[i][2], acc[i][3]);
    if (OMODE == 0) {
      *(float4*)&out[(long)r * N + c0] = v;
    } else if (OMODE == 1) {
      int b = r >> 10, tt = r & 1023, h = c0 >> 6, d = c0 & 63;
      long off = ((long)(b * H_ + h) * T_ + tt) * DK + d;
      if (OUTBF) {
        uint2 pk;
        pk.x = (unsigned)f2bf(v.x) | ((unsigned)f2bf(v.y) << 16);
        pk.y = (unsigned)f2bf(v.z) | ((unsigned)f2bf(v.w) << 16);
        *(uint2*)&outb[off] = pk;
      } else {
        *(float4*)&out[off] = v;
      }
    } else {
      int b = (int)bz >> 3, h = (int)bz & 7;
      *(float4*)&out[(long)(b * T_ + r) * DM + h * DK + c0] = v;
    }
  }
}

// ---------------------------------------------------------------------------
// Fused logits, 512 threads / 8 waves, 4 barriers total.
//   Stage   : ALL 8 heads' Q/K halo rows (34 rows, row stride 64 ch = 128 B,
//             seg ^= row&7 XOR swizzle -> conflict-free ds_read/ds_write).
//   Phase A : 36 jobs = 9 tiles x 4 head-pairs over 8 waves (balanced 5/4).
//             Results buffered in REGISTERS (mbuf), no LDS C traffic until
//             one write pass after a single barrier.
//   C layout: pixel-slot swizzle slot = pix ^ ((pix>>2)&3), channel-half
//             parity swizzle half ^= pix&1  -> <=2-way banks on all C access.
//   Phase B0: prev halo channel-last (pairwise float2 loads, gx always even).
//   Phase B1: Mt = conv3(prev)+tb as GEMM -> C channels 8..15
//   Phase B2: logits = (conv3(cat(M,Mt))+ab)/8 -> A region of d_out.
// LDS union: QKall (69632 B) aliases C (36992) + P (20736) -> 69632 B total,
// 2 blocks/CU (139 KB < 160 KB), 16 waves/CU.
// ---------------------------------------------------------------------------
__global__ __launch_bounds__(512, 4)
void fused_logits(const unsigned short* __restrict__ Qp,
                  const unsigned short* __restrict__ Kp,
                  const float* __restrict__ prev,
                  const float* __restrict__ tw, const float* __restrict__ tb,
                  const float* __restrict__ aw, const float* __restrict__ ab,
                  float* __restrict__ logits) {
  __shared__ __align__(16) unsigned short SM[34816];  // 69632 B
  unsigned short* QKl = SM;          // [ha(16)][row(34)][64]  (ha = h*2+arr)
  unsigned short* C   = SM;          // 1156 pixels * 16 ch    (18496 ushort)
  unsigned short* P   = SM + 18496;  // 1296 pixels * 8 ch     (10368 ushort)

  const int t = threadIdx.x;
  const int b = blockIdx.z, q0 = blockIdx.y * 32, k0 = blockIdx.x * 32;
  const int wave = t >> 6, lane = t & 63;
  const int lrow = lane & 15, quad = lane >> 4;
  const int o = lrow;              // out-channel for B fragments / D columns

  // ---- per-lane weight B-fragments (registers) ---------------------------
  bf16x8 W2f[5], W1f[3];
#pragma unroll
  for (int ks = 0; ks < 5; ++ks) {
    int kk0 = ks * 32 + quad * 8;           // tap = kk0>>4, i = (kk0&15)+j
    bf16x8 f = {0, 0, 0, 0, 0, 0, 0, 0};
    if (o < 8 && kk0 < 144) {
      int tap = kk0 >> 4, ib = kk0 & 15;
#pragma unroll
      for (int j = 0; j < 8; ++j)
        f[j] = (short)f2bf(aw[o * 144 + (ib + j) * 9 + tap]);
    }
    W2f[ks] = f;
  }
#pragma unroll
  for (int ks = 0; ks < 3; ++ks) {
    int kk0 = ks * 32 + quad * 8;           // tap = kk0>>3, i = j
    bf16x8 f = {0, 0, 0, 0, 0, 0, 0, 0};
    if (o < 8 && kk0 < 72) {
      int tap = kk0 >> 3;
#pragma unroll
      for (int j = 0; j < 8; ++j)
        f[j] = (short)f2bf(tw[o * 72 + j * 9 + tap]);
    }
    W1f[ks] = f;
  }
  const float tb_r = (o < 8) ? tb[o] : 0.f;
  const float ab_r = (o < 8) ? ab[o] : 0.f;

  // ---- Stage: all 8 heads, Q and K halos, 34 rows each -------------------
  // unit c = ha*272 + row*8 + seg ; ha = h*2+arr
  for (int c = t; c < 4352; c += 512) {
    int seg = c & 7;
    int rc = c >> 3;                 // ha*34 + row
    int ha = rc / 34;
    int row = rc - ha * 34;
    int h = ha >> 1, arr = ha & 1;
    int srow = (arr ? k0 : q0) - 1 + row;
    bf16x8 v = {0, 0, 0, 0, 0, 0, 0, 0};
    if (srow >= 0 && srow < T_) {
      const unsigned short* src =
          (arr ? Kp : Qp) + ((long)((b * H_ + h) * T_ + srow)) * DK + seg * 8;
      v = *(const bf16x8*)src;
    }
    *(bf16x8*)&QKl[rc * 64 + ((seg ^ (row & 7)) * 8)] = v;
  }
  __syncthreads();

  // ---- Phase A: 36 jobs (9 tiles x 4 hp), wave w owns hp=w&3,
  //      tiles (w>>2)+2s -> waves 0-3: {0,2,4,6,8}, waves 4-7: {1,3,5,7} ----
  const int hp = wave & 3;
  const int hb = hp * 4;             // region base: ha = hp*4 + {0,1,2,3}
  unsigned mbuf[5][4];
#pragma unroll
  for (int s = 0; s < 5; ++s) {
    int tile = (wave >> 2) + 2 * s;
    if (tile <= 8) {
      int ti = tile / 3, tj = tile - ti * 3;
      int rA = ti * 16 + lrow; rA = rA > 33 ? 33 : rA;  // clamp: dup row 33,
      int rB = tj * 16 + lrow; rB = rB > 33 ? 33 : rB;  // outputs discarded
      const unsigned short* pA0 = &QKl[((hb + 0) * 34 + rA) * 64];
      const unsigned short* pB0 = &QKl[((hb + 1) * 34 + rB) * 64];
      const unsigned short* pA1 = &QKl[((hb + 2) * 34 + rA) * 64];
      const unsigned short* pB1 = &QKl[((hb + 3) * 34 + rB) * 64];
      const int swA = rA & 7, swB = rB & 7;
      f32x4 acc0 = {0.f, 0.f, 0.f, 0.f};
      f32x4 acc1 = {0.f, 0.f, 0.f, 0.f};
#pragma unroll
      for (int c = 0; c < 2; ++c) {
        int sr = c * 4 + quad;
        bf16x8 a0 = *(const bf16x8*)&pA0[(sr ^ swA) * 8];
        bf16x8 b0 = *(const bf16x8*)&pB0[(sr ^ swB) * 8];
        acc0 = __builtin_amdgcn_mfma_f32_16x16x32_bf16(a0, b0, acc0, 0, 0, 0);
        bf16x8 a1 = *(const bf16x8*)&pA1[(sr ^ swA) * 8];
        bf16x8 b1 = *(const bf16x8*)&pB1[(sr ^ swB) * 8];
        acc1 = __builtin_amdgcn_mfma_f32_16x16x32_bf16(a1, b1, acc1, 0, 0, 0);
      }
#pragma unroll
      for (int r = 0; r < 4; ++r)
        mbuf[s][r] =
            (unsigned)f2bf(acc0[r]) | ((unsigned)f2bf(acc1[r]) << 16);
    }
  }
  __syncthreads();   // all MFMA reads of QKl done; C/P regions now writable

  // ---- C write pass (regs -> C, M channels) ------------------------------
#pragma unroll
  for (int s = 0; s < 5; ++s) {
    int tile = (wave >> 2) + 2 * s;
    if (tile <= 8) {
      int ti = tile / 3, tj = tile - ti * 3;
#pragma unroll
      for (int r = 0; r < 4; ++r) {
        int row = ti * 16 + quad * 4 + r, col = tj * 16 + lrow;
        if (row < 34 && col < 34) {
          int pix = row * 34 + col;
          int slot = pix ^ ((pix >> 2) & 3);
          *(unsigned*)&C[slot * 16 + (pix & 1) * 8 + hp * 2] = mbuf[s][r];
        }
      }
    }
  }

  // ---- Phase B0: prev halo, channel-last, pairwise float2 ----------------
  for (int u = t; u < 648; u += 512) {     // 1296 px as 648 row-pairs
    int p2 = u * 2;
    int row = p2 / 36, col = p2 - row * 36;  // col even (36 even)
    int gy = q0 - 2 + row, gx = k0 - 2 + col;  // gx even -> 8B aligned
    bf16x8 v0 = {0, 0, 0, 0, 0, 0, 0, 0};
    bf16x8 v1 = {0, 0, 0, 0, 0, 0, 0, 0};
    if (gy >= 0 && gy < T_) {
      const float* src = prev + ((long)(b * H_) * T_ + gy) * T_ + gx;
      bool ia = (gx >= 0 && gx < T_), ib = (gx + 1 >= 0 && gx + 1 < T_);
      if (ia && ib) {
#pragma unroll
        for (int ch = 0; ch < 8; ++ch) {
          float2 w = *(const float2*)&src[(long)ch * T_ * T_];
          v0[ch] = (short)f2bf(w.x);
          v1[ch] = (short)f2bf(w.y);
        }
      } else {
        if (ia) {
#pragma unroll
          for (int ch = 0; ch < 8; ++ch)
            v0[ch] = (short)f2bf(src[(long)ch * T_ * T_]);
        }
        if (ib) {
#pragma unroll
          for (int ch = 0; ch < 8; ++ch)
            v1[ch] = (short)f2bf(src[(long)ch * T_ * T_ + 1]);
        }
      }
    }
    *(bf16x8*)&P[p2 * 8] = v0;
    *(bf16x8*)&P[(p2 + 1) * 8] = v1;
  }
  __syncthreads();

  // ---- Phase B1: Mt = conv1(prev)+tb -> C channels 8..15 ------------------
  for (int mt = wave; mt < 73; mt += 8) {  // 1156 px in 73 m-tiles of 16
    int pin = mt * 16 + lrow;
    if (pin > 1155) pin = 1155;            // pad pixels: valid addr, discarded
    int yi = pin / 34, xi = pin - yi * 34;
    f32x4 acc = {0.f, 0.f, 0.f, 0.f};
#pragma unroll
    for (int ks = 0; ks < 3; ++ks) {
      int tap = ks * 4 + quad;             // kk0>>3
      if (tap > 8) tap = 8;                // pad k: B frag is 0
      int dy = tap / 3, dx = tap - dy * 3;
      bf16x8 av = *(const bf16x8*)&P[((yi + dy) * 36 + xi + dx) * 8];
      acc = __builtin_amdgcn_mfma_f32_16x16x32_bf16(av, W1f[ks], acc, 0, 0, 0);
    }
#pragma unroll
    for (int r = 0; r < 4; ++r) {
      int po = mt * 16 + quad * 4 + r;
      if (o < 8 && po < 1156) {
        int yo = po / 34, xo = po - yo * 34;
        int gy = q0 - 1 + yo, gx = k0 - 1 + xo;
        float val = (gy >= 0 && gy < T_ && gx >= 0 && gx < T_) ? acc[r] + tb_r
                                                               : 0.f;
        int slot = po ^ ((po >> 2) & 3);
        C[slot * 16 + ((po & 1) ^ 1) * 8 + o] = f2bf(val);
      }
    }
  }
  __syncthreads();

  // ---- Phase B2: logits = (conv2(cat)+ab)/8 -> A region -------------------
  for (int mt = wave; mt < 64; mt += 8) {  // 1024 px in 64 m-tiles
    int pin = mt * 16 + lrow;
    int yi = pin >> 5, xi = pin & 31;
    f32x4 acc = {0.f, 0.f, 0.f, 0.f};
#pragma unroll
    for (int ks = 0; ks < 5; ++ks) {
      int tap = ks * 2 + (quad >> 1);      // kk0>>4
      if (tap > 8) tap = 8;                // pad k: B frag is 0
      int dy = tap / 3, dx = tap - dy * 3;
      int p2 = (yi + dy) * 34 + (xi + dx);
      int slot = p2 ^ ((p2 >> 2) & 3);
      bf16x8 av =
          *(const bf16x8*)&C[slot * 16 + (((quad & 1) ^ (p2 & 1))) * 8];
      acc = __builtin_amdgcn_mfma_f32_16x16x32_bf16(av, W2f[ks], acc, 0, 0, 0);
    }
#pragma unroll
    for (int r = 0; r < 4; ++r) {
      int po = mt * 16 + quad * 4 + r;
      if (o < 8) {
        int yo = po >> 5, xo = po & 31;
        logits[((long)(b * H_ + o) * T_ + q0 + yo) * T_ + k0 + xo] =
            (acc[r] + ab_r) * 0.125f;
      }
    }
  }
}

// ---------------------------------------------------------------------------
// In-place masked softmax over the last dim (one row of 1024 per block).
// ---------------------------------------------------------------------------
__global__ __launch_bounds__(256)
void softmax_rows(float* __restrict__ A, const int* __restrict__ mask) {
  const int t = threadIdx.x;
  const int q = blockIdx.x, h = blockIdx.y, b = blockIdx.z;
  float* row = A + ((long)(b * H_ + h) * T_ + q) * T_;
  float4 v = *(float4*)&row[t * 4];
  int4 mv = *(const int4*)&mask[b * T_ + t * 4];
  v.x = (mv.x == 0) ? -1e9f : v.x;
  v.y = (mv.y == 0) ? -1e9f : v.y;
  v.z = (mv.z == 0) ? -1e9f : v.z;
  v.w = (mv.w == 0) ? -1e9f : v.w;

  __shared__ float r1[4], r2[4];
  const int wave = t >> 6, lane = t & 63;

  float mx4 = fmaxf(fmaxf(v.x, v.y), fmaxf(v.z, v.w));
  for (int of = 32; of > 0; of >>= 1) mx4 = fmaxf(mx4, __shfl_xor(mx4, of, 64));
  if (lane == 0) r1[wave] = mx4;
  __syncthreads();
  float mx = fmaxf(fmaxf(r1[0], r1[1]), fmaxf(r1[2], r1[3]));

  float e0 = __expf(v.x - mx), e1 = __expf(v.y - mx);
  float e2 = __expf(v.z - mx), e3 = __expf(v.w - mx);
  float s4 = (e0 + e1) + (e2 + e3);
  for (int of = 32; of > 0; of >>= 1) s4 += __shfl_xor(s4, of, 64);
  if (lane == 0) r2[wave] = s4;
  __syncthreads();
  float inv = 1.0f / (r2[0] + r2[1] + r2[2] + r2[3]);

  float4 ov;
  ov.x = e0 * inv; ov.y = e1 * inv; ov.z = e2 * inv; ov.w = e3 * inv;
  *(float4*)&row[t * 4] = ov;
}

// ---------------------------------------------------------------------------
extern "C" void kernel_launch(void* const* d_in, const int* in_sizes, int n_in,
                              void* d_out, int out_size, void* d_ws,
                              size_t ws_size, hipStream_t stream) {
  const float* q    = (const float*)d_in[0];
  const float* k    = (const float*)d_in[1];
  const float* v    = (const float*)d_in[2];
  const int*   mask = (const int*)  d_in[3];
  const float* prev = (const float*)d_in[4];
  const float* w_q  = (const float*)d_in[5];
  const float* w_k  = (const float*)d_in[6];
  const float* w_v  = (const float*)d_in[7];
  const float* w_o  = (const float*)d_in[8];
  const float* tw   = (const float*)d_in[9];
  const float* tb   = (const float*)d_in[10];
  const float* aw   = (const float*)d_in[11];
  const float* ab   = (const float*)d_in[12];

  float* out  = (float*)d_out;
  float* Aout = out + (long)B_ * T_ * DM;   // A region: (4,8,1024,1024) f32

  char* wsb = (char*)d_ws;                   // 24 MiB used
  unsigned short* Qp = (unsigned short*)wsb;                     // 4 MB bf16
  unsigned short* Kp = (unsigned short*)(wsb + (4L << 20));      // 4 MB bf16
  float* Vp  = (float*)(wsb + (8L << 20));                       // 8 MB f32
  float* ctx = (float*)(wsb + (16L << 20));                      // 8 MB f32

  dim3 blk(256);

  // Q/K projections -> bf16 head-split; V -> f32 head-split
  gemm64<0, 1, 1><<<dim3(8, 64, 1), blk, 0, stream>>>(q, w_q, Qp, 4096, 512, 512, 0, 0);
  gemm64<0, 1, 1><<<dim3(8, 64, 1), blk, 0, stream>>>(k, w_k, Kp, 4096, 512, 512, 0, 0);
  gemm64<0, 1, 0><<<dim3(8, 64, 1), blk, 0, stream>>>(v, w_v, Vp, 4096, 512, 512, 0, 0);

  // fused M + convs -> logits (into A region), all-MFMA, 512 threads
  fused_logits<<<dim3(32, 32, 4), dim3(512), 0, stream>>>(Qp, Kp, prev, tw, tb,
                                                          aw, ab, Aout);

  // softmax in place on A region
  softmax_rows<<<dim3(1024, 8, 4), blk, 0, stream>>>(Aout, mask);

  // ctx = A @ V (batched over (b,h)), output interleaved (b,t,h*64+d)
  gemm64<1, 2, 0><<<dim3(1, 16, 32), blk, 0, stream>>>(Aout, Vp, ctx, 1024, 64, 1024,
                                                       (long)T_ * T_, (long)T_ * DK);

  // final projection: ctx @ w_o^T -> out
  gemm64<0, 0, 0><<<dim3(8, 64, 1), blk, 0, stream>>>(ctx, w_o, out, 4096, 512, 512, 0, 0);
}

// Round 3
// 620.875 us; speedup vs baseline: 1.2389x; 1.1532x over previous
//
#include <hip/hip_runtime.h>
#include <hip/hip_bf16.h>

#define B_ 4
#define T_ 1024
#define DM 512
#define H_ 8
#define DK 64

typedef __attribute__((ext_vector_type(4))) float f32x4;
typedef __attribute__((ext_vector_type(8))) short bf16x8;

__device__ __forceinline__ unsigned short f2bf(float f) {
  __hip_bfloat16 h = __float2bfloat16(f);
  return *reinterpret_cast<unsigned short*>(&h);
}

// split f32 into bf16 hi + bf16 lo (x ~= hi + lo, |err| ~ 2^-18 |x|)
__device__ __forceinline__ void split2(float x, short& hi, short& lo) {
  unsigned short h = f2bf(x);
  float fh = __uint_as_float(((unsigned)h) << 16);
  unsigned short l = f2bf(x - fh);
  hi = (short)h; lo = (short)l;
}

// ---------------------------------------------------------------------------
// bf16x3 MFMA GEMM: D[M,N] = X[M,K] @ W[N,K]^T  (both f32, NT layout).
// 64x64 tile, 256 thr (4 waves, 32x32 quadrant each), K-step 32.
// hi/lo split staged in LDS with 16B-chunk XOR swizzle (chunk ^= (row>>1)&3):
// staging writes and fragment reads both verified 8-words/bank balanced.
// 3 MFMA per fragment pair: hi*hi + hi*lo + lo*hi (lo*lo dropped, ~2^-18).
//  OMODE 0: out f32 row-major [M,N]
//  OMODE 1: qkv split: row r=(b,t), col c=(h,d) -> out[b,h,t,d]; OUTBF: bf16
// ---------------------------------------------------------------------------
template<int OMODE, int OUTBF>
__global__ __launch_bounds__(256)
void proj_mfma(const float* __restrict__ X, const float* __restrict__ W,
               void* __restrict__ outv, int M, int N, int K) {
  float* out = (float*)outv;
  unsigned short* outb = (unsigned short*)outv;
  __shared__ __align__(16) unsigned short Ah[2048], Al[2048];  // [64][32]
  __shared__ __align__(16) unsigned short Bh[2048], Bl[2048];
  const int t = threadIdx.x;
  const int n0 = blockIdx.x * 64, m0 = blockIdx.y * 64;
  const int wave = t >> 6, lane = t & 63;
  const int lrow = lane & 15, quad = lane >> 4;
  const int wm = wave & 1, wn = wave >> 1;
  const int srow = t >> 2, skc = t & 3;           // staging: 64 rows x 4 chunks
  const int sbase = srow * 32 + ((skc ^ ((srow >> 1) & 3)) * 8);
  const int cswz = quad ^ ((lrow >> 1) & 3);      // fragment-read chunk swizzle
  f32x4 acc[2][2] = {};

  for (int k0 = 0; k0 < K; k0 += 32) {
    {  // stage X rows
      const float* p = &X[(long)(m0 + srow) * K + k0 + skc * 8];
      float4 v0 = *(const float4*)p, v1 = *(const float4*)(p + 4);
      float xs[8] = {v0.x, v0.y, v0.z, v0.w, v1.x, v1.y, v1.z, v1.w};
      bf16x8 hh, ll;
#pragma unroll
      for (int i = 0; i < 8; ++i) { short h, l; split2(xs[i], h, l); hh[i] = h; ll[i] = l; }
      *(bf16x8*)&Ah[sbase] = hh; *(bf16x8*)&Al[sbase] = ll;
    }
    {  // stage W rows (n-side)
      const float* p = &W[(long)(n0 + srow) * K + k0 + skc * 8];
      float4 v0 = *(const float4*)p, v1 = *(const float4*)(p + 4);
      float xs[8] = {v0.x, v0.y, v0.z, v0.w, v1.x, v1.y, v1.z, v1.w};
      bf16x8 hh, ll;
#pragma unroll
      for (int i = 0; i < 8; ++i) { short h, l; split2(xs[i], h, l); hh[i] = h; ll[i] = l; }
      *(bf16x8*)&Bh[sbase] = hh; *(bf16x8*)&Bl[sbase] = ll;
    }
    __syncthreads();
    bf16x8 ahv[2], alv[2], bhv[2], blv[2];
#pragma unroll
    for (int f = 0; f < 2; ++f) {
      int ra = (wm * 32 + f * 16 + lrow) * 32 + cswz * 8;
      ahv[f] = *(const bf16x8*)&Ah[ra];
      alv[f] = *(const bf16x8*)&Al[ra];
      int rb = (wn * 32 + f * 16 + lrow) * 32 + cswz * 8;
      bhv[f] = *(const bf16x8*)&Bh[rb];
      blv[f] = *(const bf16x8*)&Bl[rb];
    }
#pragma unroll
    for (int fi = 0; fi < 2; ++fi)
#pragma unroll
      for (int fj = 0; fj < 2; ++fj) {
        acc[fi][fj] = __builtin_amdgcn_mfma_f32_16x16x32_bf16(alv[fi], bhv[fj], acc[fi][fj], 0, 0, 0);
        acc[fi][fj] = __builtin_amdgcn_mfma_f32_16x16x32_bf16(ahv[fi], blv[fj], acc[fi][fj], 0, 0, 0);
        acc[fi][fj] = __builtin_amdgcn_mfma_f32_16x16x32_bf16(ahv[fi], bhv[fj], acc[fi][fj], 0, 0, 0);
      }
    __syncthreads();
  }

#pragma unroll
  for (int fi = 0; fi < 2; ++fi)
#pragma unroll
    for (int fj = 0; fj < 2; ++fj)
#pragma unroll
      for (int r = 0; r < 4; ++r) {
        int row = m0 + wm * 32 + fi * 16 + quad * 4 + r;
        int col = n0 + wn * 32 + fj * 16 + lrow;
        float v = acc[fi][fj][r];
        if (OMODE == 0) {
          out[(long)row * N + col] = v;
        } else {
          int b = row >> 10, tt = row & 1023, h = col >> 6, d = col & 63;
          long off = ((long)(b * H_ + h) * T_ + tt) * DK + d;
          if (OUTBF) outb[off] = f2bf(v);
          else       out[off] = v;
        }
      }
}

// ---------------------------------------------------------------------------
// Fused masked-softmax + (A @ V) via bf16x3 MFMA. One block = 64 rows of A
// for one (b,h); n-grid = 1 so the block sees full rows (K = T = 1024).
//  Prologue: per-row online max/sum over the raw logits (4 threads/row).
//  Main loop: stage exp(a-mx)*inv (softmax applied on the fly), write the
//  normalized A back to global (the mandatory A output), hi/lo split in LDS,
//  V staged transposed ([n][k]) via per-k coalesced column loads.
// Replaces the separate softmax kernel: -134 MB HBM read, -134 MB write.
// ---------------------------------------------------------------------------
__global__ __launch_bounds__(256)
void softmax_av(float* __restrict__ A, const float* __restrict__ Vp,
                float* __restrict__ ctx, const int* __restrict__ mask) {
  __shared__ __align__(16) unsigned short Ah[2048], Al[2048];  // [64][32]
  __shared__ __align__(16) unsigned short Bh[2048], Bl[2048];  // [n=64][k=32]
  __shared__ float sm[64][4], ss[64][4];
  const int t = threadIdx.x;
  const int bh = blockIdx.y, b = bh >> 3, h = bh & 7;
  const int m0 = blockIdx.x * 64;
  A += (long)bh * T_ * T_;
  const float* V = Vp + (long)bh * T_ * DK;
  const int wave = t >> 6, lane = t & 63;
  const int lrow = lane & 15, quad = lane >> 4;
  const int wm = wave & 1, wn = wave >> 1;
  const int srow = t >> 2, skc = t & 3;
  float* arow_p = &A[(long)(m0 + srow) * T_];

  // ---- prologue: per-row max & sum (online, one read pass) ----------------
  float pm = -3.0e38f, ps = 0.f;
  {
    const int cb = skc * 256;
    for (int c = 0; c < 256; c += 4) {
      float4 v = *(const float4*)&arow_p[cb + c];
      int4 mk = *(const int4*)&mask[b * T_ + cb + c];
      float x0 = mk.x ? v.x : -1e9f;
      float x1 = mk.y ? v.y : -1e9f;
      float x2 = mk.z ? v.z : -1e9f;
      float x3 = mk.w ? v.w : -1e9f;
      float m4 = fmaxf(fmaxf(x0, x1), fmaxf(x2, x3));
      if (m4 > pm) { ps *= __expf(pm - m4); pm = m4; }
      ps += __expf(x0 - pm) + __expf(x1 - pm) + __expf(x2 - pm) + __expf(x3 - pm);
    }
  }
  sm[srow][skc] = pm; ss[srow][skc] = ps;
  __syncthreads();
  const float rmx = fmaxf(fmaxf(sm[srow][0], sm[srow][1]),
                          fmaxf(sm[srow][2], sm[srow][3]));
  const float rsum = ss[srow][0] * __expf(sm[srow][0] - rmx)
                   + ss[srow][1] * __expf(sm[srow][1] - rmx)
                   + ss[srow][2] * __expf(sm[srow][2] - rmx)
                   + ss[srow][3] * __expf(sm[srow][3] - rmx);
  const float rinv = 1.0f / rsum;

  const int sbase = srow * 32 + ((skc ^ ((srow >> 1) & 3)) * 8);
  const int vn = t & 63, vkg = t >> 6;            // V staging: n=lane, k-octet=wave
  const int bbase = vn * 32 + ((vkg ^ ((vn >> 1) & 3)) * 8);
  const int cswz = quad ^ ((lrow >> 1) & 3);
  f32x4 acc[2][2] = {};

  for (int k0 = 0; k0 < T_; k0 += 32) {
    __syncthreads();                              // prev MFMA reads done
    {  // stage A rows with softmax transform; write normalized A back
      float* p = &arow_p[k0 + skc * 8];
      float4 v0 = *(const float4*)p, v1 = *(const float4*)(p + 4);
      int4 mk0 = *(const int4*)&mask[b * T_ + k0 + skc * 8];
      int4 mk1 = *(const int4*)&mask[b * T_ + k0 + skc * 8 + 4];
      float e[8];
      e[0] = __expf((mk0.x ? v0.x : -1e9f) - rmx) * rinv;
      e[1] = __expf((mk0.y ? v0.y : -1e9f) - rmx) * rinv;
      e[2] = __expf((mk0.z ? v0.z : -1e9f) - rmx) * rinv;
      e[3] = __expf((mk0.w ? v0.w : -1e9f) - rmx) * rinv;
      e[4] = __expf((mk1.x ? v1.x : -1e9f) - rmx) * rinv;
      e[5] = __expf((mk1.y ? v1.y : -1e9f) - rmx) * rinv;
      e[6] = __expf((mk1.z ? v1.z : -1e9f) - rmx) * rinv;
      e[7] = __expf((mk1.w ? v1.w : -1e9f) - rmx) * rinv;
      *(float4*)p = make_float4(e[0], e[1], e[2], e[3]);
      *(float4*)(p + 4) = make_float4(e[4], e[5], e[6], e[7]);
      bf16x8 hh, ll;
#pragma unroll
      for (int i = 0; i < 8; ++i) { short hi_, lo_; split2(e[i], hi_, lo_); hh[i] = hi_; ll[i] = lo_; }
      *(bf16x8*)&Ah[sbase] = hh; *(bf16x8*)&Al[sbase] = ll;
    }
    {  // stage V transposed: thread owns col vn, k-octet vkg
      bf16x8 hh, ll;
#pragma unroll
      for (int j = 0; j < 8; ++j) {
        float x = V[(long)(k0 + vkg * 8 + j) * DK + vn];
        short hi_, lo_; split2(x, hi_, lo_); hh[j] = hi_; ll[j] = lo_;
      }
      *(bf16x8*)&Bh[bbase] = hh; *(bf16x8*)&Bl[bbase] = ll;
    }
    __syncthreads();
    bf16x8 ahv[2], alv[2], bhv[2], blv[2];
#pragma unroll
    for (int f = 0; f < 2; ++f) {
      int ra = (wm * 32 + f * 16 + lrow) * 32 + cswz * 8;
      ahv[f] = *(const bf16x8*)&Ah[ra];
      alv[f] = *(const bf16x8*)&Al[ra];
      int rb = (wn * 32 + f * 16 + lrow) * 32 + cswz * 8;
      bhv[f] = *(const bf16x8*)&Bh[rb];
      blv[f] = *(const bf16x8*)&Bl[rb];
    }
#pragma unroll
    for (int fi = 0; fi < 2; ++fi)
#pragma unroll
      for (int fj = 0; fj < 2; ++fj) {
        acc[fi][fj] = __builtin_amdgcn_mfma_f32_16x16x32_bf16(alv[fi], bhv[fj], acc[fi][fj], 0, 0, 0);
        acc[fi][fj] = __builtin_amdgcn_mfma_f32_16x16x32_bf16(ahv[fi], blv[fj], acc[fi][fj], 0, 0, 0);
        acc[fi][fj] = __builtin_amdgcn_mfma_f32_16x16x32_bf16(ahv[fi], bhv[fj], acc[fi][fj], 0, 0, 0);
      }
  }

#pragma unroll
  for (int fi = 0; fi < 2; ++fi)
#pragma unroll
    for (int fj = 0; fj < 2; ++fj)
#pragma unroll
      for (int r = 0; r < 4; ++r) {
        int row = m0 + wm * 32 + fi * 16 + quad * 4 + r;
        int col = wn * 32 + fj * 16 + lrow;
        ctx[(long)(b * T_ + row) * DM + h * DK + col] = acc[fi][fj][r];
      }
}

// ---------------------------------------------------------------------------
// Fused logits, 512 threads / 8 waves, 4 barriers total. (Unchanged from R2.)
// ---------------------------------------------------------------------------
__global__ __launch_bounds__(512, 4)
void fused_logits(const unsigned short* __restrict__ Qp,
                  const unsigned short* __restrict__ Kp,
                  const float* __restrict__ prev,
                  const float* __restrict__ tw, const float* __restrict__ tb,
                  const float* __restrict__ aw, const float* __restrict__ ab,
                  float* __restrict__ logits) {
  __shared__ __align__(16) unsigned short SM[34816];  // 69632 B
  unsigned short* QKl = SM;          // [ha(16)][row(34)][64]  (ha = h*2+arr)
  unsigned short* C   = SM;          // 1156 pixels * 16 ch    (18496 ushort)
  unsigned short* P   = SM + 18496;  // 1296 pixels * 8 ch     (10368 ushort)

  const int t = threadIdx.x;
  const int b = blockIdx.z, q0 = blockIdx.y * 32, k0 = blockIdx.x * 32;
  const int wave = t >> 6, lane = t & 63;
  const int lrow = lane & 15, quad = lane >> 4;
  const int o = lrow;

  bf16x8 W2f[5], W1f[3];
#pragma unroll
  for (int ks = 0; ks < 5; ++ks) {
    int kk0 = ks * 32 + quad * 8;
    bf16x8 f = {0, 0, 0, 0, 0, 0, 0, 0};
    if (o < 8 && kk0 < 144) {
      int tap = kk0 >> 4, ib = kk0 & 15;
#pragma unroll
      for (int j = 0; j < 8; ++j)
        f[j] = (short)f2bf(aw[o * 144 + (ib + j) * 9 + tap]);
    }
    W2f[ks] = f;
  }
#pragma unroll
  for (int ks = 0; ks < 3; ++ks) {
    int kk0 = ks * 32 + quad * 8;
    bf16x8 f = {0, 0, 0, 0, 0, 0, 0, 0};
    if (o < 8 && kk0 < 72) {
      int tap = kk0 >> 3;
#pragma unroll
      for (int j = 0; j < 8; ++j)
        f[j] = (short)f2bf(tw[o * 72 + j * 9 + tap]);
    }
    W1f[ks] = f;
  }
  const float tb_r = (o < 8) ? tb[o] : 0.f;
  const float ab_r = (o < 8) ? ab[o] : 0.f;

  for (int c = t; c < 4352; c += 512) {
    int seg = c & 7;
    int rc = c >> 3;
    int ha = rc / 34;
    int row = rc - ha * 34;
    int h = ha >> 1, arr = ha & 1;
    int srow = (arr ? k0 : q0) - 1 + row;
    bf16x8 v = {0, 0, 0, 0, 0, 0, 0, 0};
    if (srow >= 0 && srow < T_) {
      const unsigned short* src =
          (arr ? Kp : Qp) + ((long)((b * H_ + h) * T_ + srow)) * DK + seg * 8;
      v = *(const bf16x8*)src;
    }
    *(bf16x8*)&QKl[rc * 64 + ((seg ^ (row & 7)) * 8)] = v;
  }
  __syncthreads();

  const int hp = wave & 3;
  const int hb = hp * 4;
  unsigned mbuf[5][4];
#pragma unroll
  for (int s = 0; s < 5; ++s) {
    int tile = (wave >> 2) + 2 * s;
    if (tile <= 8) {
      int ti = tile / 3, tj = tile - ti * 3;
      int rA = ti * 16 + lrow; rA = rA > 33 ? 33 : rA;
      int rB = tj * 16 + lrow; rB = rB > 33 ? 33 : rB;
      const unsigned short* pA0 = &QKl[((hb + 0) * 34 + rA) * 64];
      const unsigned short* pB0 = &QKl[((hb + 1) * 34 + rB) * 64];
      const unsigned short* pA1 = &QKl[((hb + 2) * 34 + rA) * 64];
      const unsigned short* pB1 = &QKl[((hb + 3) * 34 + rB) * 64];
      const int swA = rA & 7, swB = rB & 7;
      f32x4 acc0 = {0.f, 0.f, 0.f, 0.f};
      f32x4 acc1 = {0.f, 0.f, 0.f, 0.f};
#pragma unroll
      for (int c = 0; c < 2; ++c) {
        int sr = c * 4 + quad;
        bf16x8 a0 = *(const bf16x8*)&pA0[(sr ^ swA) * 8];
        bf16x8 b0 = *(const bf16x8*)&pB0[(sr ^ swB) * 8];
        acc0 = __builtin_amdgcn_mfma_f32_16x16x32_bf16(a0, b0, acc0, 0, 0, 0);
        bf16x8 a1 = *(const bf16x8*)&pA1[(sr ^ swA) * 8];
        bf16x8 b1 = *(const bf16x8*)&pB1[(sr ^ swB) * 8];
        acc1 = __builtin_amdgcn_mfma_f32_16x16x32_bf16(a1, b1, acc1, 0, 0, 0);
      }
#pragma unroll
      for (int r = 0; r < 4; ++r)
        mbuf[s][r] =
            (unsigned)f2bf(acc0[r]) | ((unsigned)f2bf(acc1[r]) << 16);
    }
  }
  __syncthreads();

#pragma unroll
  for (int s = 0; s < 5; ++s) {
    int tile = (wave >> 2) + 2 * s;
    if (tile <= 8) {
      int ti = tile / 3, tj = tile - ti * 3;
#pragma unroll
      for (int r = 0; r < 4; ++r) {
        int row = ti * 16 + quad * 4 + r, col = tj * 16 + lrow;
        if (row < 34 && col < 34) {
          int pix = row * 34 + col;
          int slot = pix ^ ((pix >> 2) & 3);
          *(unsigned*)&C[slot * 16 + (pix & 1) * 8 + hp * 2] = mbuf[s][r];
        }
      }
    }
  }

  for (int u = t; u < 648; u += 512) {
    int p2 = u * 2;
    int row = p2 / 36, col = p2 - row * 36;
    int gy = q0 - 2 + row, gx = k0 - 2 + col;
    bf16x8 v0 = {0, 0, 0, 0, 0, 0, 0, 0};
    bf16x8 v1 = {0, 0, 0, 0, 0, 0, 0, 0};
    if (gy >= 0 && gy < T_) {
      const float* src = prev + ((long)(b * H_) * T_ + gy) * T_ + gx;
      bool ia = (gx >= 0 && gx < T_), ib = (gx + 1 >= 0 && gx + 1 < T_);
      if (ia && ib) {
#pragma unroll
        for (int ch = 0; ch < 8; ++ch) {
          float2 w = *(const float2*)&src[(long)ch * T_ * T_];
          v0[ch] = (short)f2bf(w.x);
          v1[ch] = (short)f2bf(w.y);
        }
      } else {
        if (ia) {
#pragma unroll
          for (int ch = 0; ch < 8; ++ch)
            v0[ch] = (short)f2bf(src[(long)ch * T_ * T_]);
        }
        if (ib) {
#pragma unroll
          for (int ch = 0; ch < 8; ++ch)
            v1[ch] = (short)f2bf(src[(long)ch * T_ * T_ + 1]);
        }
      }
    }
    *(bf16x8*)&P[p2 * 8] = v0;
    *(bf16x8*)&P[(p2 + 1) * 8] = v1;
  }
  __syncthreads();

  for (int mt = wave; mt < 73; mt += 8) {
    int pin = mt * 16 + lrow;
    if (pin > 1155) pin = 1155;
    int yi = pin / 34, xi = pin - yi * 34;
    f32x4 acc = {0.f, 0.f, 0.f, 0.f};
#pragma unroll
    for (int ks = 0; ks < 3; ++ks) {
      int tap = ks * 4 + quad;
      if (tap > 8) tap = 8;
      int dy = tap / 3, dx = tap - dy * 3;
      bf16x8 av = *(const bf16x8*)&P[((yi + dy) * 36 + xi + dx) * 8];
      acc = __builtin_amdgcn_mfma_f32_16x16x32_bf16(av, W1f[ks], acc, 0, 0, 0);
    }
#pragma unroll
    for (int r = 0; r < 4; ++r) {
      int po = mt * 16 + quad * 4 + r;
      if (o < 8 && po < 1156) {
        int yo = po / 34, xo = po - yo * 34;
        int gy = q0 - 1 + yo, gx = k0 - 1 + xo;
        float val = (gy >= 0 && gy < T_ && gx >= 0 && gx < T_) ? acc[r] + tb_r
                                                               : 0.f;
        int slot = po ^ ((po >> 2) & 3);
        C[slot * 16 + ((po & 1) ^ 1) * 8 + o] = f2bf(val);
      }
    }
  }
  __syncthreads();

  for (int mt = wave; mt < 64; mt += 8) {
    int pin = mt * 16 + lrow;
    int yi = pin >> 5, xi = pin & 31;
    f32x4 acc = {0.f, 0.f, 0.f, 0.f};
#pragma unroll
    for (int ks = 0; ks < 5; ++ks) {
      int tap = ks * 2 + (quad >> 1);
      if (tap > 8) tap = 8;
      int dy = tap / 3, dx = tap - dy * 3;
      int p2 = (yi + dy) * 34 + (xi + dx);
      int slot = p2 ^ ((p2 >> 2) & 3);
      bf16x8 av =
          *(const bf16x8*)&C[slot * 16 + (((quad & 1) ^ (p2 & 1))) * 8];
      acc = __builtin_amdgcn_mfma_f32_16x16x32_bf16(av, W2f[ks], acc, 0, 0, 0);
    }
#pragma unroll
    for (int r = 0; r < 4; ++r) {
      int po = mt * 16 + quad * 4 + r;
      if (o < 8) {
        int yo = po >> 5, xo = po & 31;
        logits[((long)(b * H_ + o) * T_ + q0 + yo) * T_ + k0 + xo] =
            (acc[r] + ab_r) * 0.125f;
      }
    }
  }
}

// ---------------------------------------------------------------------------
extern "C" void kernel_launch(void* const* d_in, const int* in_sizes, int n_in,
                              void* d_out, int out_size, void* d_ws,
                              size_t ws_size, hipStream_t stream) {
  const float* q    = (const float*)d_in[0];
  const float* k    = (const float*)d_in[1];
  const float* v    = (const float*)d_in[2];
  const int*   mask = (const int*)  d_in[3];
  const float* prev = (const float*)d_in[4];
  const float* w_q  = (const float*)d_in[5];
  const float* w_k  = (const float*)d_in[6];
  const float* w_v  = (const float*)d_in[7];
  const float* w_o  = (const float*)d_in[8];
  const float* tw   = (const float*)d_in[9];
  const float* tb   = (const float*)d_in[10];
  const float* aw   = (const float*)d_in[11];
  const float* ab   = (const float*)d_in[12];

  float* out  = (float*)d_out;
  float* Aout = out + (long)B_ * T_ * DM;   // A region: (4,8,1024,1024) f32

  char* wsb = (char*)d_ws;                   // 24 MiB used
  unsigned short* Qp = (unsigned short*)wsb;                     // 4 MB bf16
  unsigned short* Kp = (unsigned short*)(wsb + (4L << 20));      // 4 MB bf16
  float* Vp  = (float*)(wsb + (8L << 20));                       // 8 MB f32
  float* ctx = (float*)(wsb + (16L << 20));                      // 8 MB f32

  dim3 blk(256);

  // Q/K projections -> bf16 head-split; V -> f32 head-split (bf16x3 MFMA)
  proj_mfma<1, 1><<<dim3(8, 64), blk, 0, stream>>>(q, w_q, Qp, 4096, 512, 512);
  proj_mfma<1, 1><<<dim3(8, 64), blk, 0, stream>>>(k, w_k, Kp, 4096, 512, 512);
  proj_mfma<1, 0><<<dim3(8, 64), blk, 0, stream>>>(v, w_v, Vp, 4096, 512, 512);

  // fused M + convs -> raw logits (into A region)
  fused_logits<<<dim3(32, 32, 4), dim3(512), 0, stream>>>(Qp, Kp, prev, tw, tb,
                                                          aw, ab, Aout);

  // softmax (in place, normalized A is the output) + A @ V, bf16x3 MFMA
  softmax_av<<<dim3(16, 32), blk, 0, stream>>>(Aout, Vp, ctx, mask);

  // final projection: ctx @ w_o^T -> out (bf16x3 MFMA)
  proj_mfma<0, 0><<<dim3(8, 64), blk, 0, stream>>>(ctx, w_o, out, 4096, 512, 512);
}

// Round 4
// 619.999 us; speedup vs baseline: 1.2406x; 1.0014x over previous
//
#include <hip/hip_runtime.h>
#include <hip/hip_bf16.h>

#define B_ 4
#define T_ 1024
#define DM 512
#define H_ 8
#define DK 64

typedef __attribute__((ext_vector_type(4))) float f32x4;
typedef __attribute__((ext_vector_type(8))) short bf16x8;

__device__ __forceinline__ unsigned short f2bf(float f) {
  __hip_bfloat16 h = __float2bfloat16(f);
  return *reinterpret_cast<unsigned short*>(&h);
}

// split f32 into bf16 hi + bf16 lo (x ~= hi + lo, |err| ~ 2^-18 |x|)
__device__ __forceinline__ void split2(float x, short& hi, short& lo) {
  unsigned short h = f2bf(x);
  float fh = __uint_as_float(((unsigned)h) << 16);
  unsigned short l = f2bf(x - fh);
  hi = (short)h; lo = (short)l;
}

// ---------------------------------------------------------------------------
// bf16x3 MFMA GEMM: D[M,N] = X[M,K] @ W[N,K]^T  (both f32, NT layout).
// 64x64 tile, 256 thr (4 waves, 32x32 quadrant each), K-step 32.
//  OMODE 0: out f32 row-major [M,N]
//  OMODE 1: qkv split: row r=(b,t), col c=(h,d) -> out[b,h,t,d]; OUTBF: bf16
// ---------------------------------------------------------------------------
template<int OMODE, int OUTBF>
__global__ __launch_bounds__(256)
void proj_mfma(const float* __restrict__ X, const float* __restrict__ W,
               void* __restrict__ outv, int M, int N, int K) {
  float* out = (float*)outv;
  unsigned short* outb = (unsigned short*)outv;
  __shared__ __align__(16) unsigned short Ah[2048], Al[2048];  // [64][32]
  __shared__ __align__(16) unsigned short Bh[2048], Bl[2048];
  const int t = threadIdx.x;
  const int n0 = blockIdx.x * 64, m0 = blockIdx.y * 64;
  const int wave = t >> 6, lane = t & 63;
  const int lrow = lane & 15, quad = lane >> 4;
  const int wm = wave & 1, wn = wave >> 1;
  const int srow = t >> 2, skc = t & 3;           // staging: 64 rows x 4 chunks
  const int sbase = srow * 32 + ((skc ^ ((srow >> 1) & 3)) * 8);
  const int cswz = quad ^ ((lrow >> 1) & 3);      // fragment-read chunk swizzle
  f32x4 acc[2][2] = {};

  for (int k0 = 0; k0 < K; k0 += 32) {
    {  // stage X rows
      const float* p = &X[(long)(m0 + srow) * K + k0 + skc * 8];
      float4 v0 = *(const float4*)p, v1 = *(const float4*)(p + 4);
      float xs[8] = {v0.x, v0.y, v0.z, v0.w, v1.x, v1.y, v1.z, v1.w};
      bf16x8 hh, ll;
#pragma unroll
      for (int i = 0; i < 8; ++i) { short h, l; split2(xs[i], h, l); hh[i] = h; ll[i] = l; }
      *(bf16x8*)&Ah[sbase] = hh; *(bf16x8*)&Al[sbase] = ll;
    }
    {  // stage W rows (n-side)
      const float* p = &W[(long)(n0 + srow) * K + k0 + skc * 8];
      float4 v0 = *(const float4*)p, v1 = *(const float4*)(p + 4);
      float xs[8] = {v0.x, v0.y, v0.z, v0.w, v1.x, v1.y, v1.z, v1.w};
      bf16x8 hh, ll;
#pragma unroll
      for (int i = 0; i < 8; ++i) { short h, l; split2(xs[i], h, l); hh[i] = h; ll[i] = l; }
      *(bf16x8*)&Bh[sbase] = hh; *(bf16x8*)&Bl[sbase] = ll;
    }
    __syncthreads();
    bf16x8 ahv[2], alv[2], bhv[2], blv[2];
#pragma unroll
    for (int f = 0; f < 2; ++f) {
      int ra = (wm * 32 + f * 16 + lrow) * 32 + cswz * 8;
      ahv[f] = *(const bf16x8*)&Ah[ra];
      alv[f] = *(const bf16x8*)&Al[ra];
      int rb = (wn * 32 + f * 16 + lrow) * 32 + cswz * 8;
      bhv[f] = *(const bf16x8*)&Bh[rb];
      blv[f] = *(const bf16x8*)&Bl[rb];
    }
#pragma unroll
    for (int fi = 0; fi < 2; ++fi)
#pragma unroll
      for (int fj = 0; fj < 2; ++fj) {
        acc[fi][fj] = __builtin_amdgcn_mfma_f32_16x16x32_bf16(alv[fi], bhv[fj], acc[fi][fj], 0, 0, 0);
        acc[fi][fj] = __builtin_amdgcn_mfma_f32_16x16x32_bf16(ahv[fi], blv[fj], acc[fi][fj], 0, 0, 0);
        acc[fi][fj] = __builtin_amdgcn_mfma_f32_16x16x32_bf16(ahv[fi], bhv[fj], acc[fi][fj], 0, 0, 0);
      }
    __syncthreads();
  }

#pragma unroll
  for (int fi = 0; fi < 2; ++fi)
#pragma unroll
    for (int fj = 0; fj < 2; ++fj)
#pragma unroll
      for (int r = 0; r < 4; ++r) {
        int row = m0 + wm * 32 + fi * 16 + quad * 4 + r;
        int col = n0 + wn * 32 + fj * 16 + lrow;
        float v = acc[fi][fj][r];
        if (OMODE == 0) {
          out[(long)row * N + col] = v;
        } else {
          int b = row >> 10, tt = row & 1023, h = col >> 6, d = col & 63;
          long off = ((long)(b * H_ + h) * T_ + tt) * DK + d;
          if (OUTBF) outb[off] = f2bf(v);
          else       out[off] = v;
        }
      }
}

// ---------------------------------------------------------------------------
// Per-row masked max + 1/sum(exp) over the raw logits. One WAVE per row,
// fully coalesced (each instruction = 1 KB contiguous), 64-lane shuffle
// reduce. stats[row] = {rowmax, 1/rowsum}. Replaces softmax_av's serial
// 4-threads/row online prologue.
// ---------------------------------------------------------------------------
__global__ __launch_bounds__(256)
void row_reduce(const float* __restrict__ A, const int* __restrict__ mask,
                float2* __restrict__ stats) {
  const int t = threadIdx.x;
  const int wave = t >> 6, lane = t & 63;
  const long row = (long)blockIdx.x * 4 + wave;      // [0, B_*H_*T_)
  const int b = (int)(row >> 13);                    // row / (H_*T_)
  const float* rp = A + row * T_;
  const int* mp = mask + b * T_;
  float x[16];
#pragma unroll
  for (int j = 0; j < 4; ++j) {
    float4 v = *(const float4*)&rp[(j * 64 + lane) * 4];
    int4 m = *(const int4*)&mp[(j * 64 + lane) * 4];
    x[j * 4 + 0] = m.x ? v.x : -1e9f;
    x[j * 4 + 1] = m.y ? v.y : -1e9f;
    x[j * 4 + 2] = m.z ? v.z : -1e9f;
    x[j * 4 + 3] = m.w ? v.w : -1e9f;
  }
  float mx = x[0];
#pragma unroll
  for (int j = 1; j < 16; ++j) mx = fmaxf(mx, x[j]);
  for (int of = 32; of > 0; of >>= 1) mx = fmaxf(mx, __shfl_xor(mx, of, 64));
  float s = 0.f;
#pragma unroll
  for (int j = 0; j < 16; ++j) s += __expf(x[j] - mx);
  for (int of = 32; of > 0; of >>= 1) s += __shfl_xor(s, of, 64);
  if (lane == 0) stats[row] = make_float2(mx, 1.0f / s);
}

// ---------------------------------------------------------------------------
// Fused masked-softmax apply + (A @ V) via bf16x3 MFMA. One block = 64 rows
// of A for one (b,h). Row stats precomputed by row_reduce -> MFMA starts
// immediately. Writes the normalized A back (mandatory output) + ctx.
// ---------------------------------------------------------------------------
__global__ __launch_bounds__(256)
void softmax_av(float* __restrict__ A, const float* __restrict__ Vp,
                float* __restrict__ ctx, const int* __restrict__ mask,
                const float2* __restrict__ stats) {
  __shared__ __align__(16) unsigned short Ah[2048], Al[2048];  // [64][32]
  __shared__ __align__(16) unsigned short Bh[2048], Bl[2048];  // [n=64][k=32]
  const int t = threadIdx.x;
  const int bh = blockIdx.y, b = bh >> 3, h = bh & 7;
  const int m0 = blockIdx.x * 64;
  A += (long)bh * T_ * T_;
  const float* V = Vp + (long)bh * T_ * DK;
  const int wave = t >> 6, lane = t & 63;
  const int lrow = lane & 15, quad = lane >> 4;
  const int wm = wave & 1, wn = wave >> 1;
  const int srow = t >> 2, skc = t & 3;
  float* arow_p = &A[(long)(m0 + srow) * T_];

  const float2 st = stats[(long)bh * T_ + m0 + srow];
  const float rmx = st.x, rinv = st.y;

  const int sbase = srow * 32 + ((skc ^ ((srow >> 1) & 3)) * 8);
  const int vn = t & 63, vkg = t >> 6;            // V staging: n=lane, k-octet=wave
  const int bbase = vn * 32 + ((vkg ^ ((vn >> 1) & 3)) * 8);
  const int cswz = quad ^ ((lrow >> 1) & 3);
  f32x4 acc[2][2] = {};

  for (int k0 = 0; k0 < T_; k0 += 32) {
    __syncthreads();                              // prev MFMA reads done
    {  // stage A rows with softmax transform; write normalized A back
      float* p = &arow_p[k0 + skc * 8];
      float4 v0 = *(const float4*)p, v1 = *(const float4*)(p + 4);
      int4 mk0 = *(const int4*)&mask[b * T_ + k0 + skc * 8];
      int4 mk1 = *(const int4*)&mask[b * T_ + k0 + skc * 8 + 4];
      float e[8];
      e[0] = __expf((mk0.x ? v0.x : -1e9f) - rmx) * rinv;
      e[1] = __expf((mk0.y ? v0.y : -1e9f) - rmx) * rinv;
      e[2] = __expf((mk0.z ? v0.z : -1e9f) - rmx) * rinv;
      e[3] = __expf((mk0.w ? v0.w : -1e9f) - rmx) * rinv;
      e[4] = __expf((mk1.x ? v1.x : -1e9f) - rmx) * rinv;
      e[5] = __expf((mk1.y ? v1.y : -1e9f) - rmx) * rinv;
      e[6] = __expf((mk1.z ? v1.z : -1e9f) - rmx) * rinv;
      e[7] = __expf((mk1.w ? v1.w : -1e9f) - rmx) * rinv;
      *(float4*)p = make_float4(e[0], e[1], e[2], e[3]);
      *(float4*)(p + 4) = make_float4(e[4], e[5], e[6], e[7]);
      bf16x8 hh, ll;
#pragma unroll
      for (int i = 0; i < 8; ++i) { short hi_, lo_; split2(e[i], hi_, lo_); hh[i] = hi_; ll[i] = lo_; }
      *(bf16x8*)&Ah[sbase] = hh; *(bf16x8*)&Al[sbase] = ll;
    }
    {  // stage V transposed: thread owns col vn, k-octet vkg
      bf16x8 hh, ll;
#pragma unroll
      for (int j = 0; j < 8; ++j) {
        float x = V[(long)(k0 + vkg * 8 + j) * DK + vn];
        short hi_, lo_; split2(x, hi_, lo_); hh[j] = hi_; ll[j] = lo_;
      }
      *(bf16x8*)&Bh[bbase] = hh; *(bf16x8*)&Bl[bbase] = ll;
    }
    __syncthreads();
    bf16x8 ahv[2], alv[2], bhv[2], blv[2];
#pragma unroll
    for (int f = 0; f < 2; ++f) {
      int ra = (wm * 32 + f * 16 + lrow) * 32 + cswz * 8;
      ahv[f] = *(const bf16x8*)&Ah[ra];
      alv[f] = *(const bf16x8*)&Al[ra];
      int rb = (wn * 32 + f * 16 + lrow) * 32 + cswz * 8;
      bhv[f] = *(const bf16x8*)&Bh[rb];
      blv[f] = *(const bf16x8*)&Bl[rb];
    }
#pragma unroll
    for (int fi = 0; fi < 2; ++fi)
#pragma unroll
      for (int fj = 0; fj < 2; ++fj) {
        acc[fi][fj] = __builtin_amdgcn_mfma_f32_16x16x32_bf16(alv[fi], bhv[fj], acc[fi][fj], 0, 0, 0);
        acc[fi][fj] = __builtin_amdgcn_mfma_f32_16x16x32_bf16(ahv[fi], blv[fj], acc[fi][fj], 0, 0, 0);
        acc[fi][fj] = __builtin_amdgcn_mfma_f32_16x16x32_bf16(ahv[fi], bhv[fj], acc[fi][fj], 0, 0, 0);
      }
  }

#pragma unroll
  for (int fi = 0; fi < 2; ++fi)
#pragma unroll
    for (int fj = 0; fj < 2; ++fj)
#pragma unroll
      for (int r = 0; r < 4; ++r) {
        int row = m0 + wm * 32 + fi * 16 + quad * 4 + r;
        int col = wn * 32 + fj * 16 + lrow;
        ctx[(long)(b * T_ + row) * DM + h * DK + col] = acc[fi][fj][r];
      }
}

// ---------------------------------------------------------------------------
// helper: early prev loads (T14). Loads 2 pixels x 8 channels for unit u
// into f[16] (even idx = left pixel, odd = right). Flags say which are valid.
// ---------------------------------------------------------------------------
__device__ __forceinline__ void prev_early(const float* __restrict__ prev,
                                           int b, int q0, int k0, int u,
                                           float* f, bool& ok0, bool& ok1) {
  int p2 = u * 2;
  int row = p2 / 36, col = p2 - row * 36;    // col even
  int gy = q0 - 2 + row, gx = k0 - 2 + col;
  ok0 = ok1 = false;
  if (gy >= 0 && gy < T_) {
    const float* src = prev + ((long)(b * H_) * T_ + gy) * T_ + gx;
    bool ia = (gx >= 0 && gx < T_), ib = (gx + 1 >= 0 && gx + 1 < T_);
    if (ia && ib) {
#pragma unroll
      for (int ch = 0; ch < 8; ++ch) {
        float2 w = *(const float2*)&src[(long)ch * T_ * T_];
        f[ch * 2] = w.x; f[ch * 2 + 1] = w.y;
      }
      ok0 = ok1 = true;
    } else {
      if (ia) {
#pragma unroll
        for (int ch = 0; ch < 8; ++ch) f[ch * 2] = src[(long)ch * T_ * T_];
        ok0 = true;
      }
      if (ib) {
#pragma unroll
        for (int ch = 0; ch < 8; ++ch) f[ch * 2 + 1] = src[(long)ch * T_ * T_ + 1];
        ok1 = true;
      }
    }
  }
}

// ---------------------------------------------------------------------------
// Fused logits, 512 threads / 8 waves.
//   T14: prev global loads issued at kernel start (registers), consumed at
//   the B0 site after phase A -> HBM latency hidden under QK stage + MFMA.
//   B1 epilogue divisions reduced to 1 per tile (incremental xo/yo carry).
// ---------------------------------------------------------------------------
__global__ __launch_bounds__(512, 4)
void fused_logits(const unsigned short* __restrict__ Qp,
                  const unsigned short* __restrict__ Kp,
                  const float* __restrict__ prev,
                  const float* __restrict__ tw, const float* __restrict__ tb,
                  const float* __restrict__ aw, const float* __restrict__ ab,
                  float* __restrict__ logits) {
  __shared__ __align__(16) unsigned short SM[34816];  // 69632 B
  unsigned short* QKl = SM;          // [ha(16)][row(34)][64]  (ha = h*2+arr)
  unsigned short* C   = SM;          // 1156 pixels * 16 ch    (18496 ushort)
  unsigned short* P   = SM + 18496;  // 1296 pixels * 8 ch     (10368 ushort)

  const int t = threadIdx.x;
  const int b = blockIdx.z, q0 = blockIdx.y * 32, k0 = blockIdx.x * 32;
  const int wave = t >> 6, lane = t & 63;
  const int lrow = lane & 15, quad = lane >> 4;
  const int o = lrow;

  // ---- T14: issue prev loads NOW; consumed after phase A ------------------
  float pvA[16], pvB[16];
  bool okA0, okA1, okB0 = false, okB1 = false;
  prev_early(prev, b, q0, k0, t, pvA, okA0, okA1);
  if (t < 136) prev_early(prev, b, q0, k0, t + 512, pvB, okB0, okB1);

  bf16x8 W2f[5], W1f[3];
#pragma unroll
  for (int ks = 0; ks < 5; ++ks) {
    int kk0 = ks * 32 + quad * 8;
    bf16x8 f = {0, 0, 0, 0, 0, 0, 0, 0};
    if (o < 8 && kk0 < 144) {
      int tap = kk0 >> 4, ib = kk0 & 15;
#pragma unroll
      for (int j = 0; j < 8; ++j)
        f[j] = (short)f2bf(aw[o * 144 + (ib + j) * 9 + tap]);
    }
    W2f[ks] = f;
  }
#pragma unroll
  for (int ks = 0; ks < 3; ++ks) {
    int kk0 = ks * 32 + quad * 8;
    bf16x8 f = {0, 0, 0, 0, 0, 0, 0, 0};
    if (o < 8 && kk0 < 72) {
      int tap = kk0 >> 3;
#pragma unroll
      for (int j = 0; j < 8; ++j)
        f[j] = (short)f2bf(tw[o * 72 + j * 9 + tap]);
    }
    W1f[ks] = f;
  }
  const float tb_r = (o < 8) ? tb[o] : 0.f;
  const float ab_r = (o < 8) ? ab[o] : 0.f;

  for (int c = t; c < 4352; c += 512) {
    int seg = c & 7;
    int rc = c >> 3;
    int ha = rc / 34;
    int row = rc - ha * 34;
    int h = ha >> 1, arr = ha & 1;
    int srow = (arr ? k0 : q0) - 1 + row;
    bf16x8 v = {0, 0, 0, 0, 0, 0, 0, 0};
    if (srow >= 0 && srow < T_) {
      const unsigned short* src =
          (arr ? Kp : Qp) + ((long)((b * H_ + h) * T_ + srow)) * DK + seg * 8;
      v = *(const bf16x8*)src;
    }
    *(bf16x8*)&QKl[rc * 64 + ((seg ^ (row & 7)) * 8)] = v;
  }
  __syncthreads();

  const int hp = wave & 3;
  const int hb = hp * 4;
  unsigned mbuf[5][4];
#pragma unroll
  for (int s = 0; s < 5; ++s) {
    int tile = (wave >> 2) + 2 * s;
    if (tile <= 8) {
      int ti = tile / 3, tj = tile - ti * 3;
      int rA = ti * 16 + lrow; rA = rA > 33 ? 33 : rA;
      int rB = tj * 16 + lrow; rB = rB > 33 ? 33 : rB;
      const unsigned short* pA0 = &QKl[((hb + 0) * 34 + rA) * 64];
      const unsigned short* pB0 = &QKl[((hb + 1) * 34 + rB) * 64];
      const unsigned short* pA1 = &QKl[((hb + 2) * 34 + rA) * 64];
      const unsigned short* pB1 = &QKl[((hb + 3) * 34 + rB) * 64];
      const int swA = rA & 7, swB = rB & 7;
      f32x4 acc0 = {0.f, 0.f, 0.f, 0.f};
      f32x4 acc1 = {0.f, 0.f, 0.f, 0.f};
#pragma unroll
      for (int c = 0; c < 2; ++c) {
        int sr = c * 4 + quad;
        bf16x8 a0 = *(const bf16x8*)&pA0[(sr ^ swA) * 8];
        bf16x8 b0 = *(const bf16x8*)&pB0[(sr ^ swB) * 8];
        acc0 = __builtin_amdgcn_mfma_f32_16x16x32_bf16(a0, b0, acc0, 0, 0, 0);
        bf16x8 a1 = *(const bf16x8*)&pA1[(sr ^ swA) * 8];
        bf16x8 b1 = *(const bf16x8*)&pB1[(sr ^ swB) * 8];
        acc1 = __builtin_amdgcn_mfma_f32_16x16x32_bf16(a1, b1, acc1, 0, 0, 0);
      }
#pragma unroll
      for (int r = 0; r < 4; ++r)
        mbuf[s][r] =
            (unsigned)f2bf(acc0[r]) | ((unsigned)f2bf(acc1[r]) << 16);
    }
  }
  __syncthreads();

  // ---- C write pass (regs -> C, M channels) ------------------------------
#pragma unroll
  for (int s = 0; s < 5; ++s) {
    int tile = (wave >> 2) + 2 * s;
    if (tile <= 8) {
      int ti = tile / 3, tj = tile - ti * 3;
#pragma unroll
      for (int r = 0; r < 4; ++r) {
        int row = ti * 16 + quad * 4 + r, col = tj * 16 + lrow;
        if (row < 34 && col < 34) {
          int pix = row * 34 + col;
          int slot = pix ^ ((pix >> 2) & 3);
          *(unsigned*)&C[slot * 16 + (pix & 1) * 8 + hp * 2] = mbuf[s][r];
        }
      }
    }
  }

  // ---- Phase B0: convert pre-loaded prev -> P (channel-last) --------------
  {
    int p2 = t * 2;
    bf16x8 v0 = {0, 0, 0, 0, 0, 0, 0, 0};
    bf16x8 v1 = {0, 0, 0, 0, 0, 0, 0, 0};
    if (okA0) {
#pragma unroll
      for (int ch = 0; ch < 8; ++ch) v0[ch] = (short)f2bf(pvA[ch * 2]);
    }
    if (okA1) {
#pragma unroll
      for (int ch = 0; ch < 8; ++ch) v1[ch] = (short)f2bf(pvA[ch * 2 + 1]);
    }
    *(bf16x8*)&P[p2 * 8] = v0;
    *(bf16x8*)&P[(p2 + 1) * 8] = v1;
  }
  if (t < 136) {
    int p2 = (t + 512) * 2;
    bf16x8 v0 = {0, 0, 0, 0, 0, 0, 0, 0};
    bf16x8 v1 = {0, 0, 0, 0, 0, 0, 0, 0};
    if (okB0) {
#pragma unroll
      for (int ch = 0; ch < 8; ++ch) v0[ch] = (short)f2bf(pvB[ch * 2]);
    }
    if (okB1) {
#pragma unroll
      for (int ch = 0; ch < 8; ++ch) v1[ch] = (short)f2bf(pvB[ch * 2 + 1]);
    }
    *(bf16x8*)&P[p2 * 8] = v0;
    *(bf16x8*)&P[(p2 + 1) * 8] = v1;
  }
  __syncthreads();

  // ---- Phase B1: Mt = conv1(prev)+tb -> C channels 8..15 ------------------
  for (int mt = wave; mt < 73; mt += 8) {
    int pin = mt * 16 + lrow;
    if (pin > 1155) pin = 1155;
    int yi = pin / 34, xi = pin - yi * 34;
    f32x4 acc = {0.f, 0.f, 0.f, 0.f};
#pragma unroll
    for (int ks = 0; ks < 3; ++ks) {
      int tap = ks * 4 + quad;
      if (tap > 8) tap = 8;
      int dy = tap / 3, dx = tap - dy * 3;
      bf16x8 av = *(const bf16x8*)&P[((yi + dy) * 36 + xi + dx) * 8];
      acc = __builtin_amdgcn_mfma_f32_16x16x32_bf16(av, W1f[ks], acc, 0, 0, 0);
    }
    int po0 = mt * 16 + quad * 4;
    int yo = po0 / 34, xo = po0 - yo * 34;   // 1 division; carry below
#pragma unroll
    for (int r = 0; r < 4; ++r) {
      int po = po0 + r;
      if (o < 8 && po < 1156) {
        int gy = q0 - 1 + yo, gx = k0 - 1 + xo;
        float val = (gy >= 0 && gy < T_ && gx >= 0 && gx < T_) ? acc[r] + tb_r
                                                               : 0.f;
        int slot = po ^ ((po >> 2) & 3);
        C[slot * 16 + ((po & 1) ^ 1) * 8 + o] = f2bf(val);
      }
      xo++;
      if (xo == 34) { xo = 0; yo++; }
    }
  }
  __syncthreads();

  // ---- Phase B2: logits = (conv2(cat)+ab)/8 -> A region -------------------
  for (int mt = wave; mt < 64; mt += 8) {
    int pin = mt * 16 + lrow;
    int yi = pin >> 5, xi = pin & 31;
    f32x4 acc = {0.f, 0.f, 0.f, 0.f};
#pragma unroll
    for (int ks = 0; ks < 5; ++ks) {
      int tap = ks * 2 + (quad >> 1);
      if (tap > 8) tap = 8;
      int dy = tap / 3, dx = tap - dy * 3;
      int p2 = (yi + dy) * 34 + (xi + dx);
      int slot = p2 ^ ((p2 >> 2) & 3);
      bf16x8 av =
          *(const bf16x8*)&C[slot * 16 + (((quad & 1) ^ (p2 & 1))) * 8];
      acc = __builtin_amdgcn_mfma_f32_16x16x32_bf16(av, W2f[ks], acc, 0, 0, 0);
    }
#pragma unroll
    for (int r = 0; r < 4; ++r) {
      int po = mt * 16 + quad * 4 + r;
      if (o < 8) {
        int yo = po >> 5, xo = po & 31;
        logits[((long)(b * H_ + o) * T_ + q0 + yo) * T_ + k0 + xo] =
            (acc[r] + ab_r) * 0.125f;
      }
    }
  }
}

// ---------------------------------------------------------------------------
extern "C" void kernel_launch(void* const* d_in, const int* in_sizes, int n_in,
                              void* d_out, int out_size, void* d_ws,
                              size_t ws_size, hipStream_t stream) {
  const float* q    = (const float*)d_in[0];
  const float* k    = (const float*)d_in[1];
  const float* v    = (const float*)d_in[2];
  const int*   mask = (const int*)  d_in[3];
  const float* prev = (const float*)d_in[4];
  const float* w_q  = (const float*)d_in[5];
  const float* w_k  = (const float*)d_in[6];
  const float* w_v  = (const float*)d_in[7];
  const float* w_o  = (const float*)d_in[8];
  const float* tw   = (const float*)d_in[9];
  const float* tb   = (const float*)d_in[10];
  const float* aw   = (const float*)d_in[11];
  const float* ab   = (const float*)d_in[12];

  float* out  = (float*)d_out;
  float* Aout = out + (long)B_ * T_ * DM;   // A region: (4,8,1024,1024) f32

  char* wsb = (char*)d_ws;                   // 24 MiB used
  unsigned short* Qp = (unsigned short*)wsb;                     // 4 MB bf16
  unsigned short* Kp = (unsigned short*)(wsb + (4L << 20));      // 4 MB bf16
  float* Vp  = (float*)(wsb + (8L << 20));                       // 8 MB f32
  float* ctx = (float*)(wsb + (16L << 20));                      // 8 MB f32
  // row stats reuse the Qp region (dead after fused_logits): 32768 float2
  float2* stats = (float2*)wsb;

  dim3 blk(256);

  // Q/K projections -> bf16 head-split; V -> f32 head-split (bf16x3 MFMA)
  proj_mfma<1, 1><<<dim3(8, 64), blk, 0, stream>>>(q, w_q, Qp, 4096, 512, 512);
  proj_mfma<1, 1><<<dim3(8, 64), blk, 0, stream>>>(k, w_k, Kp, 4096, 512, 512);
  proj_mfma<1, 0><<<dim3(8, 64), blk, 0, stream>>>(v, w_v, Vp, 4096, 512, 512);

  // fused M + convs -> raw logits (into A region)
  fused_logits<<<dim3(32, 32, 4), dim3(512), 0, stream>>>(Qp, Kp, prev, tw, tb,
                                                          aw, ab, Aout);

  // per-row max & inv-sum (wave per row, coalesced)
  row_reduce<<<dim3(8192), blk, 0, stream>>>(Aout, mask, stats);

  // softmax apply (in place, normalized A is the output) + A @ V
  softmax_av<<<dim3(16, 32), blk, 0, stream>>>(Aout, Vp, ctx, mask, stats);

  // final projection: ctx @ w_o^T -> out (bf16x3 MFMA)
  proj_mfma<0, 0><<<dim3(8, 64), blk, 0, stream>>>(ctx, w_o, out, 4096, 512, 512);
}